// Round 11
// baseline (8980.386 us; speedup 1.0000x reference)
//
#include <hip/hip_runtime.h>

typedef unsigned int u32;
typedef unsigned long long u64;
typedef float f32x2 __attribute__((ext_vector_type(2)));

#define N_PTS 16384
#define N_S   8192
#define NB    10
#define CHID  64
#define COUT  128
#define R2    0.0625f
#define NCELL 4096

// ======================= sort: morton counting sort =======================
__device__ __forceinline__ u32 spread3(u32 v) {  // 4 bits -> every 3rd bit
  return (v & 1u) | ((v & 2u) << 2) | ((v & 4u) << 4) | ((v & 8u) << 6);
}

__global__ void cell_kernel(const float* __restrict__ pos, int* __restrict__ cellid,
                            int* __restrict__ hist) {
  int i = blockIdx.x * 256 + threadIdx.x;
  float x = pos[3 * i], y = pos[3 * i + 1], z = pos[3 * i + 2];
  u32 ix = (u32)(x * 16.0f); if (ix > 15u) ix = 15u;
  u32 iy = (u32)(y * 16.0f); if (iy > 15u) iy = 15u;
  u32 iz = (u32)(z * 16.0f); if (iz > 15u) iz = 15u;
  u32 c = spread3(ix) | (spread3(iy) << 1) | (spread3(iz) << 2);
  cellid[i] = (int)c;
  atomicAdd(&hist[c], 1);
}

__global__ __launch_bounds__(1024) void scan_kernel(const int* __restrict__ hist,
                                                    int* __restrict__ base) {
  __shared__ int sp[1024];
  int t = threadIdx.x;
  int h0 = hist[4 * t], h1 = hist[4 * t + 1], h2 = hist[4 * t + 2], h3 = hist[4 * t + 3];
  int s = h0 + h1 + h2 + h3;
  int acc = s;
  sp[t] = s;
  __syncthreads();
  for (int off = 1; off < 1024; off <<= 1) {
    int v = (t >= off) ? sp[t - off] : 0;
    __syncthreads();
    acc += v;
    sp[t] = acc;
    __syncthreads();
  }
  int excl = acc - s;
  base[4 * t + 0] = excl;
  base[4 * t + 1] = excl + h0;
  base[4 * t + 2] = excl + h0 + h1;
  base[4 * t + 3] = excl + h0 + h1 + h2;
}

__global__ void scatter_kernel(const float* __restrict__ pos, const int* __restrict__ cellid,
                               int* __restrict__ base, float* __restrict__ xs,
                               float* __restrict__ ys, float* __restrict__ zs,
                               int* __restrict__ oid) {
  int i = blockIdx.x * 256 + threadIdx.x;
  int c = cellid[i];
  int d = atomicAdd(&base[c], 1);
  xs[d] = pos[3 * i]; ys[d] = pos[3 * i + 1]; zs[d] = pos[3 * i + 2];
  oid[d] = i;
}

// ======================= fused FPS + kNN + MLP =======================
// R27: fps occupies ONE CU for 6.6 ms while 255 idle; knn/mlp only need idx
// entries fps produces incrementally. Fuse: block 0 = R24-frozen fps body
// (verbatim) publishing prog=k+2 (RELEASE, AGENT) once per 32 iters; 192
// worker blocks each stage W2T/W1 + zero a tail slice (overlapped with fps),
// then per 32-center chunk: acquire-poll prog (t0-only, s_sleep-throttled),
// read idx via agent-scope relaxed atomics (L2 coherence point), run the
// R25 knn body + R26 mlp. Deadlock-safe: 193 blocks <= 256 CUs, each block's
// 134 KB LDS fits any CU alone -> all resident regardless of dispatch order.
// prog memset per replay (graph-safe, survives workspace re-poison).
// Tail after fps = ONE chunk (~30 us) instead of ~500 us serial.
#define FPS_T 1024
#define PPT   16
#define WRK   192          // worker blocks
#define NCHK  (N_S / 32)   // 256 chunks

// LDS union layout (bytes):
//  fps   : s_yz [0,131072) | s_k [131072,131328)
//  worker: s_p [0,16384) | spd [16384,57472) | spi [57472,98560)
//          | sW2T [98560,133376) | sW1 [133376,134144) | sb1 [134144,134400)
//          | sprog [134400,134404)
//  mlp scratch aliases spd (msh1) and spi (msrel) after merge completes.
#define OFF_SK   131072
#define OFF_SPD  16384
#define OFF_SPI  57472
#define OFF_W2T  98560
#define OFF_W1   133376
#define OFF_B1   134144
#define OFF_PROG 134400
#define SMEM_SZ  134432

#define KNS    32
#define KTILE  1024
#define KPAD   321   // KNS*NB=320 -> pad to 321 (==1 mod 32, conflict-free)
#define W2S    68    // W2T stride: 16B-aligned (68*4=272=17*16), bank-swept

#define PT_LIST(OP) OP(0) OP(1) OP(2) OP(3) OP(4) OP(5) OP(6) OP(7) \
                    OP(8) OP(9) OP(10) OP(11) OP(12) OP(13) OP(14) OP(15)
#define G4_LIST(OP) OP(0,0,1,2,3,0,1)   OP(1,4,5,6,7,2,3) \
                    OP(2,8,9,10,11,4,5) OP(3,12,13,14,15,6,7)
#define PR_LIST(OP) OP(0) OP(1) OP(2) OP(3) OP(4) OP(5) OP(6) OP(7)

// u64 max via positive-double max (key high word = finite positive float bits
// -> double exponent never all-ones, sign 0; positive doubles order == bit order).
__device__ __forceinline__ u64 u64fmax(u64 a, u64 b) {
  double ad = __longlong_as_double((long long)a);
  double bd = __longlong_as_double((long long)b);
  return (u64)(long long)__double_as_longlong(fmax(ad, bd));
}

template <int CTRL, int RM>
__device__ __forceinline__ u64 dppmax(u64 cur) {
  int slo = __builtin_amdgcn_update_dpp(0, (int)(u32)cur, CTRL, RM, 0xf, false);
  int shi = __builtin_amdgcn_update_dpp(0, (int)(u32)(cur >> 32), CTRL, RM, 0xf, false);
  u64 o = ((u64)(u32)shi << 32) | (u32)slo;
  return u64fmax(o, cur);
}

// packed 2xf32 ops (VOP3P). IEEE RNE per element, no contraction (opaque asm).
__device__ __forceinline__ f32x2 pk_add(f32x2 a, f32x2 b) {
  f32x2 d;
  asm("v_pk_add_f32 %0, %1, %2" : "=v"(d) : "v"(a), "v"(b));
  return d;
}
__device__ __forceinline__ f32x2 pk_mul(f32x2 a, f32x2 b) {
  f32x2 d;
  asm("v_pk_mul_f32 %0, %1, %2" : "=v"(d) : "v"(a), "v"(b));
  return d;
}

__global__ __launch_bounds__(1024, 4)
void fused_kernel(const float* __restrict__ pos,
                  const float* __restrict__ xs,
                  const float* __restrict__ ys,
                  const float* __restrict__ zs,
                  const int* __restrict__ oidv,
                  int* __restrict__ idx,
                  int* __restrict__ src,
                  int* __restrict__ valid,
                  const float* __restrict__ W1,
                  const float* __restrict__ b1,
                  const float* __restrict__ W2,
                  const float* __restrict__ b2,
                  float* __restrict__ out,
                  int* __restrict__ prog) {
  __shared__ __align__(16) unsigned char smem[SMEM_SZ];
  const int t = threadIdx.x;

  if (blockIdx.x == 0) {
    // =================== FPS (R24 body, frozen; + prog publish) ===================
    float2* s_yz = (float2*)smem;
    u64 (*s_k)[16] = (u64 (*)[16])(smem + OFF_SK);
    const int wv = t >> 6;
    const int base0 = t * PPT;
    const float4* __restrict__ xv = (const float4*)(xs + base0);
    const float4* __restrict__ yv = (const float4*)(ys + base0);
    const float4* __restrict__ zv = (const float4*)(zs + base0);
    const int4*   __restrict__ ov = (const int4*)(oidv + base0);

#define DECLP(J) float md##J;
    PT_LIST(DECLP)
#undef DECLP
#define DECLC(J) u32 C##J;
    PT_LIST(DECLC)
#undef DECLC
#define DECLX(P) f32x2 X##P; f32x2 Y##P; f32x2 Z##P;
    PR_LIST(DECLX)
#undef DECLX

    float bnx = 3.4e38f, bxx = -3.4e38f, bny = 3.4e38f, bxy = -3.4e38f,
          bnz = 3.4e38f, bxz = -3.4e38f;

#define INIT4(G, J0, J1, J2, J3, PA, PB) { \
    float4 vx = xv[G], vy = yv[G], vz = zv[G]; int4 vo = ov[G]; \
    md##J0 = 3.402823466e38f; md##J1 = 3.402823466e38f; \
    md##J2 = 3.402823466e38f; md##J3 = 3.402823466e38f; \
    X##PA.x = vx.x; X##PA.y = vx.y; X##PB.x = vx.z; X##PB.y = vx.w; \
    Y##PA.x = vy.x; Y##PA.y = vy.y; Y##PB.x = vy.z; Y##PB.y = vy.w; \
    Z##PA.x = vz.x; Z##PA.y = vz.y; Z##PB.x = vz.z; Z##PB.y = vz.w; \
    s_yz[J0 * FPS_T + t] = make_float2(vy.x, vz.x); \
    s_yz[J1 * FPS_T + t] = make_float2(vy.y, vz.y); \
    s_yz[J2 * FPS_T + t] = make_float2(vy.z, vz.z); \
    s_yz[J3 * FPS_T + t] = make_float2(vy.w, vz.w); \
    C##J0 = ((16383u - (u32)vo.x) << 14) | (u32)(base0 + J0); \
    C##J1 = ((16383u - (u32)vo.y) << 14) | (u32)(base0 + J1); \
    C##J2 = ((16383u - (u32)vo.z) << 14) | (u32)(base0 + J2); \
    C##J3 = ((16383u - (u32)vo.w) << 14) | (u32)(base0 + J3); \
    bnx = fminf(bnx, fminf(fminf(vx.x, vx.y), fminf(vx.z, vx.w))); \
    bxx = fmaxf(bxx, fmaxf(fmaxf(vx.x, vx.y), fmaxf(vx.z, vx.w))); \
    bny = fminf(bny, fminf(fminf(vy.x, vy.y), fminf(vy.z, vy.w))); \
    bxy = fmaxf(bxy, fmaxf(fmaxf(vy.x, vy.y), fmaxf(vy.z, vy.w))); \
    bnz = fminf(bnz, fminf(fminf(vz.x, vz.y), fminf(vz.z, vz.w))); \
    bxz = fmaxf(bxz, fmaxf(fmaxf(vz.x, vz.y), fmaxf(vz.z, vz.w))); }
    G4_LIST(INIT4)
#undef INIT4

    // key = md_bits<<32 | (16383-oid)<<14 | sidx. Lex max == numpy argmax.
    u64 ckey = 0;
    u64 wklast = 0;
    float cmaxf = 3.402823466e38f;
    float cx = pos[0], cy = pos[1], cz = pos[2];
    if (t == 0) idx[0] = 0;
    __syncthreads();

    for (int k = 0; k < N_S - 1; ++k) {
      float dxl = fmaxf(fmaxf(bnx - cx, cx - bxx), 0.0f);
      float dyl = fmaxf(fmaxf(bny - cy, cy - bxy), 0.0f);
      float dzl = fmaxf(fmaxf(bnz - cz, cz - bxz), 0.0f);
      float lb2 = dxl * dxl + dyl * dyl + dzl * dzl;
      bool act = (0.99f * lb2 < cmaxf);

      if (__ballot(act)) {
        if (act) {
          f32x2 ncx2; ncx2.x = -cx; ncx2.y = -cx;
          f32x2 ncy2; ncy2.x = -cy; ncy2.y = -cy;
          f32x2 ncz2; ncz2.x = -cz; ncz2.y = -cz;
          u64 bkA = 0, bkB = 0;
#define UPDP(P, J0, J1) { \
          f32x2 dx2 = pk_add(X##P, ncx2); \
          f32x2 dy2 = pk_add(Y##P, ncy2); \
          f32x2 dz2 = pk_add(Z##P, ncz2); \
          f32x2 sq = pk_add(pk_mul(dx2, dx2), pk_mul(dy2, dy2)); \
          f32x2 d2 = pk_add(sq, pk_mul(dz2, dz2)); \
          float m0 = fminf(md##J0, d2.x); md##J0 = m0; \
          bkA = u64fmax(bkA, ((u64)__float_as_uint(m0) << 32) | C##J0); \
          float m1 = fminf(md##J1, d2.y); md##J1 = m1; \
          bkB = u64fmax(bkB, ((u64)__float_as_uint(m1) << 32) | C##J1); }
          UPDP(0, 0, 1)  UPDP(1, 2, 3)  UPDP(2, 4, 5)  UPDP(3, 6, 7)
          UPDP(4, 8, 9)  UPDP(5, 10, 11) UPDP(6, 12, 13) UPDP(7, 14, 15)
#undef UPDP
          ckey = u64fmax(bkA, bkB);
          cmaxf = __uint_as_float((u32)(ckey >> 32));
        }
        u64 wk = ckey;
        wk = dppmax<0x111, 0xf>(wk);   // row_shr:1
        wk = dppmax<0x112, 0xf>(wk);   // row_shr:2
        wk = dppmax<0x114, 0xf>(wk);   // row_shr:4
        wk = dppmax<0x118, 0xf>(wk);   // row_shr:8
        wk = dppmax<0x142, 0xa>(wk);   // row_bcast:15 -> rows 1,3
        wk = dppmax<0x143, 0xc>(wk);   // row_bcast:31 -> rows 2,3
        wklast = wk;
      }
      if ((t & 63) == 63) s_k[k & 1][wv] = wklast;
      __syncthreads();

      u64 gk = s_k[k & 1][t & 15];
      gk = dppmax<0x121, 0xf>(gk);   // row_ror:1
      gk = dppmax<0x122, 0xf>(gk);   // row_ror:2
      gk = dppmax<0x124, 0xf>(gk);   // row_ror:4
      gk = dppmax<0x128, 0xf>(gk);   // row_ror:8
      u32 glo = (u32)__builtin_amdgcn_readfirstlane((int)(u32)gk);
      u32 ghi = (u32)__builtin_amdgcn_readfirstlane((int)(u32)(gk >> 32));
      u64 gmax = ((u64)ghi << 32) | glo;
      int sidx = (int)(gmax & 16383u);
      if (t == 0) {
        idx[k + 1] = 16383 - (int)((gmax >> 14) & 16383u);
        // publish at chunk boundaries (k+2 multiple of 32): release makes all
        // prior idx stores agent-visible before the counter advances.
        if ((k & 31) == 30)
          __hip_atomic_store(prog, k + 2, __ATOMIC_RELEASE, __HIP_MEMORY_SCOPE_AGENT);
      }
      int cell = (sidx & (PPT - 1)) * FPS_T + (sidx >> 4);
      cx = xs[sidx];
      float2 yz = s_yz[cell];
      cy = yz.x;
      cz = yz.y;
    }
  } else {
    // =================== worker: kNN + MLP per ready chunk ===================
    const int wid = blockIdx.x - 1;   // 0..WRK-1
    float4* s_p = (float4*)smem;
    float (*spd)[KPAD] = (float (*)[KPAD])(smem + OFF_SPD);
    int   (*spi)[KPAD] = (int (*)[KPAD])(smem + OFF_SPI);
    float* sW2T = (float*)(smem + OFF_W2T);
    float* sW1  = (float*)(smem + OFF_W1);
    float* sb1  = (float*)(smem + OFF_B1);
    int*   sprog = (int*)(smem + OFF_PROG);
    float* msh1  = (float*)(smem + OFF_SPD);   // [8][NB][CHID], after merge
    float* msrel = (float*)(smem + OFF_SPI);   // [8][NB][3], after merge

    // stage W2 transposed (stride W2S) + W1 + b1; zero a tail-row slice.
    // All overlapped with fps (no dependency yet).
    for (int e = t; e < CHID * COUT; e += 1024) {
      int kk = e >> 7, c = e & (COUT - 1);
      sW2T[c * W2S + kk] = W2[e];
    }
    if (t < 3 * CHID) sW1[t] = W1[t];
    if (t < CHID) sb1[t] = b1[t];
    {
      float4* outv = (float4*)(out + (size_t)N_S * COUT);
      const int cnt = (N_PTS - N_S) * COUT / 4;
      for (int j = wid * 1024 + t; j < cnt; j += WRK * 1024)
        outv[j] = make_float4(0.f, 0.f, 0.f, 0.f);
    }
    __syncthreads();

    for (int gc = wid; gc < NCHK; gc += WRK) {
      // ---- wait for fps to publish this chunk's 32 centers
      const int need = gc * 32 + 32;
      for (;;) {
        if (t == 0) *sprog = __hip_atomic_load(prog, __ATOMIC_ACQUIRE, __HIP_MEMORY_SCOPE_AGENT);
        __syncthreads();
        if (*sprog >= need) break;
        __builtin_amdgcn_s_sleep(32);
        __syncthreads();
      }
      // ---- kNN (R25 body): 32 centers x 32 splits
      const int sp = t >> 5;
      const int cl = t & 31;
      const int i = gc * 32 + cl;
      // agent-scope load: reads at the L2 coherence point (immune to stale L1)
      const int ci = __hip_atomic_load(idx + i, __ATOMIC_RELAXED, __HIP_MEMORY_SCOPE_AGENT);
      const float cx = pos[3 * ci], cy = pos[3 * ci + 1], cz = pos[3 * ci + 2];
      float nd[NB]; int ni[NB];
#pragma unroll
      for (int q = 0; q < NB; ++q) { nd[q] = 3.402823466e38f; ni[q] = 0x7fffffff; }

      for (int base = 0; base < N_PTS; base += KTILE) {
        __syncthreads();
        for (int j = t; j < KTILE; j += 1024) {
          int pnt = base + j;
          s_p[j] = make_float4(pos[3 * pnt], pos[3 * pnt + 1], pos[3 * pnt + 2], 0.f);
        }
        __syncthreads();
        for (int j = sp; j < KTILE; j += KNS) {
          float4 q4 = s_p[j];
          float dx = __fsub_rn(cx, q4.x);
          float dy = __fsub_rn(cy, q4.y);
          float dz = __fsub_rn(cz, q4.z);
          float d2 = __fadd_rn(__fadd_rn(__fmul_rn(dx, dx), __fmul_rn(dy, dy)), __fmul_rn(dz, dz));
          if (d2 < nd[NB - 1]) {
            float cd = d2; int cp = base + j;
#pragma unroll
            for (int q = 0; q < NB; ++q) {
              bool sw = (cd < nd[q]) || (cd == nd[q] && cp < ni[q]);
              if (sw) { float td = nd[q]; int tp = ni[q]; nd[q] = cd; ni[q] = cp; cd = td; cp = tp; }
            }
          }
        }
      }
#pragma unroll
      for (int q = 0; q < NB; ++q) { spd[cl][sp * NB + q] = nd[q]; spi[cl][sp * NB + q] = ni[q]; }
      __syncthreads();
      if (sp == 0) {
        int cur[KNS];
#pragma unroll
        for (int s = 0; s < KNS; ++s) cur[s] = 0;
        int vb = 0;
        for (int q = 0; q < NB; ++q) {
          float bd = 3.402823466e38f; int bi = 0x7fffffff; int bsl = 0;
#pragma unroll
          for (int s = 0; s < KNS; ++s) {
            float d = spd[cl][s * NB + cur[s]]; int id = spi[cl][s * NB + cur[s]];
            if (d < bd || (d == bd && id < bi)) { bd = d; bi = id; bsl = s; }
          }
#pragma unroll
          for (int s = 0; s < KNS; ++s) cur[s] += (s == bsl) ? 1 : 0;
          src[i * NB + q] = bi;
          if (bd <= R2) vb |= (1 << q);
        }
        valid[i] = vb;
      }
      __syncthreads();

      // ---- MLP (R26 math, kk-ascending fmaf): 4 rounds x 8 centers x 128 ch
      for (int r = 0; r < 4; ++r) {
        const int c8 = t >> 7;          // 0..7
        const int ch = t & 127;
        const int im = gc * 32 + r * 8 + c8;
        if (ch < NB) {
          int s = src[im * NB + ch];
          // reference subtracts pos[:s] row im, NOT the sampled center
          msrel[(c8 * NB + ch) * 3 + 0] = pos[3 * s + 0] - pos[3 * im + 0];
          msrel[(c8 * NB + ch) * 3 + 1] = pos[3 * s + 1] - pos[3 * im + 1];
          msrel[(c8 * NB + ch) * 3 + 2] = pos[3 * s + 2] - pos[3 * im + 2];
        }
        __syncthreads();
        for (int e = t; e < 8 * NB * CHID; e += 1024) {
          int kk = e & 63;
          int n = (e >> 6) % NB;
          int cc = e / (NB * CHID);
          float a = sb1[kk] + msrel[(cc * NB + n) * 3 + 0] * sW1[kk]
                            + msrel[(cc * NB + n) * 3 + 1] * sW1[64 + kk]
                            + msrel[(cc * NB + n) * 3 + 2] * sW1[128 + kk];
          msh1[(cc * NB + n) * CHID + kk] = fmaxf(a, 0.0f);
        }
        __syncthreads();
        {
          const int vmask = valid[im];
          const float bb = b2[ch];
          float m = 0.0f;
          bool any = false;
          for (int n = 0; n < NB; ++n) {
            if (vmask & (1 << n)) {
              float acc = bb;
#pragma unroll
              for (int g = 0; g < 16; ++g) {
                float4 h = *(const float4*)&msh1[(c8 * NB + n) * CHID + 4 * g];
                float4 w = *(const float4*)&sW2T[ch * W2S + 4 * g];
                acc = fmaf(h.x, w.x, acc);
                acc = fmaf(h.y, w.y, acc);
                acc = fmaf(h.z, w.z, acc);
                acc = fmaf(h.w, w.w, acc);
              }
              m = any ? fmaxf(m, acc) : acc;
              any = true;
            }
          }
          out[(size_t)im * COUT + ch] = any ? m : 0.0f;
        }
        __syncthreads();
      }
    }
  }
}

// ======================= launch =======================
extern "C" void kernel_launch(void* const* d_in, const int* in_sizes, int n_in,
                              void* d_out, int out_size, void* d_ws, size_t ws_size,
                              hipStream_t stream) {
  (void)in_sizes; (void)n_in; (void)out_size; (void)ws_size;
  const float* pos = (const float*)d_in[0];
  const float* W1 = (const float*)d_in[2];
  const float* b1 = (const float*)d_in[3];
  const float* W2 = (const float*)d_in[4];
  const float* b2 = (const float*)d_in[5];
  float* out = (float*)d_out;

  char* ws = (char*)d_ws;
  int*   idx   = (int*)ws;                 ws += (size_t)N_S * 4;          // 32 KB
  int*   src   = (int*)ws;                 ws += (size_t)N_S * NB * 4;     // 320 KB
  int*   valid = (int*)ws;                 ws += (size_t)N_S * 4;          // 32 KB
  float* xs    = (float*)ws;               ws += (size_t)N_PTS * 4;        // 64 KB
  float* ys    = (float*)ws;               ws += (size_t)N_PTS * 4;
  float* zs    = (float*)ws;               ws += (size_t)N_PTS * 4;
  int*   oid   = (int*)ws;                 ws += (size_t)N_PTS * 4;
  int*   progp = (int*)ws;                 ws += 16;                       // progress counter
  // sort temporaries alias the src region (sort completes before knn writes src)
  int* cellid = src;                 // N_PTS ints = 64 KB  (src region is 320 KB)
  int* hist   = src + N_PTS;         // NCELL ints = 16 KB
  int* basebuf= src + N_PTS + NCELL; // NCELL ints = 16 KB

  hipMemsetAsync(hist, 0, (size_t)NCELL * 4, stream);
  hipMemsetAsync(progp, 0, 4, stream);
  cell_kernel<<<N_PTS / 256, 256, 0, stream>>>(pos, cellid, hist);
  scan_kernel<<<1, 1024, 0, stream>>>(hist, basebuf);
  scatter_kernel<<<N_PTS / 256, 256, 0, stream>>>(pos, cellid, basebuf, xs, ys, zs, oid);
  fused_kernel<<<1 + WRK, 1024, 0, stream>>>(pos, xs, ys, zs, oid, idx, src, valid,
                                             W1, b1, W2, b2, out, progp);
}

// Round 12
// 6899.606 us; speedup vs baseline: 1.3016x; 1.3016x over previous
//
#include <hip/hip_runtime.h>

typedef unsigned int u32;
typedef unsigned long long u64;
typedef float f32x2 __attribute__((ext_vector_type(2)));

#define N_PTS 16384
#define N_S   8192
#define NB    10
#define CHID  64
#define COUT  128
#define R2    0.0625f
#define NCELL 4096

// ======================= sort: morton counting sort =======================
__device__ __forceinline__ u32 spread3(u32 v) {  // 4 bits -> every 3rd bit
  return (v & 1u) | ((v & 2u) << 2) | ((v & 4u) << 4) | ((v & 8u) << 6);
}

__global__ void cell_kernel(const float* __restrict__ pos, int* __restrict__ cellid,
                            int* __restrict__ hist) {
  int i = blockIdx.x * 256 + threadIdx.x;
  float x = pos[3 * i], y = pos[3 * i + 1], z = pos[3 * i + 2];
  u32 ix = (u32)(x * 16.0f); if (ix > 15u) ix = 15u;
  u32 iy = (u32)(y * 16.0f); if (iy > 15u) iy = 15u;
  u32 iz = (u32)(z * 16.0f); if (iz > 15u) iz = 15u;
  u32 c = spread3(ix) | (spread3(iy) << 1) | (spread3(iz) << 2);
  cellid[i] = (int)c;
  atomicAdd(&hist[c], 1);
}

__global__ __launch_bounds__(1024) void scan_kernel(const int* __restrict__ hist,
                                                    int* __restrict__ base) {
  __shared__ int sp[1024];
  int t = threadIdx.x;
  int h0 = hist[4 * t], h1 = hist[4 * t + 1], h2 = hist[4 * t + 2], h3 = hist[4 * t + 3];
  int s = h0 + h1 + h2 + h3;
  int acc = s;
  sp[t] = s;
  __syncthreads();
  for (int off = 1; off < 1024; off <<= 1) {
    int v = (t >= off) ? sp[t - off] : 0;
    __syncthreads();
    acc += v;
    sp[t] = acc;
    __syncthreads();
  }
  int excl = acc - s;
  base[4 * t + 0] = excl;
  base[4 * t + 1] = excl + h0;
  base[4 * t + 2] = excl + h0 + h1;
  base[4 * t + 3] = excl + h0 + h1 + h2;
}

__global__ void scatter_kernel(const float* __restrict__ pos, const int* __restrict__ cellid,
                               int* __restrict__ base, float* __restrict__ xs,
                               float* __restrict__ ys, float* __restrict__ zs,
                               int* __restrict__ oid) {
  int i = blockIdx.x * 256 + threadIdx.x;
  int c = cellid[i];
  int d = atomicAdd(&base[c], 1);
  xs[d] = pos[3 * i]; ys[d] = pos[3 * i + 1]; zs[d] = pos[3 * i + 2];
  oid[d] = i;
}

// ======================= fused FPS + kNN + MLP =======================
// R27 post-mortem: overlap worked but ACQUIRE polls emitted buffer_inv (~30
// L2-invalidates/us/XCD from 192 workers) -> no L2 retained anything -> fps's
// critical-chain xs[sidx] load went L2(~200cy) -> L3(~500cy) -> fps 6590 ->
// ~9000us. FETCH stayed low (L3 absorbed) = classic L3-masking signature.
// R28: drop the invalidates, keep the overlap.
//  - fps publishes prog with RELEASE/AGENT (buffer_wbl2 on fps's XCD only,
//    1/32 iters; wbl2 writes back dirty idx lines WITHOUT invalidating ->
//    fps's clean xs/pos lines stay L2-resident).
//  - workers poll prog and read idx with RELAXED/AGENT atomic loads: agent
//    atomics bypass the non-coherent L2 and read the L3 coherence point ->
//    they see release-ordered data with NO buffer_inv. Seeing prog>=need
//    (L3) implies the preceding wbl2 completed -> idx is in L3 -> relaxed
//    atomic idx loads read it there.
// Everything else identical to R27 (sync protocol passed correctness).
#define FPS_T 1024
#define PPT   16
#define WRK   192          // worker blocks
#define NCHK  (N_S / 32)   // 256 chunks

// LDS union layout (bytes):
//  fps   : s_yz [0,131072) | s_k [131072,131328)
//  worker: s_p [0,16384) | spd [16384,57472) | spi [57472,98560)
//          | sW2T [98560,133376) | sW1 [133376,134144) | sb1 [134144,134400)
//          | sprog [134400,134404)
//  mlp scratch aliases spd (msh1) and spi (msrel) after merge completes.
#define OFF_SK   131072
#define OFF_SPD  16384
#define OFF_SPI  57472
#define OFF_W2T  98560
#define OFF_W1   133376
#define OFF_B1   134144
#define OFF_PROG 134400
#define SMEM_SZ  134432

#define KNS    32
#define KTILE  1024
#define KPAD   321   // KNS*NB=320 -> pad to 321 (==1 mod 32, conflict-free)
#define W2S    68    // W2T stride: 16B-aligned (68*4=272=17*16), bank-swept

#define PT_LIST(OP) OP(0) OP(1) OP(2) OP(3) OP(4) OP(5) OP(6) OP(7) \
                    OP(8) OP(9) OP(10) OP(11) OP(12) OP(13) OP(14) OP(15)
#define G4_LIST(OP) OP(0,0,1,2,3,0,1)   OP(1,4,5,6,7,2,3) \
                    OP(2,8,9,10,11,4,5) OP(3,12,13,14,15,6,7)
#define PR_LIST(OP) OP(0) OP(1) OP(2) OP(3) OP(4) OP(5) OP(6) OP(7)

// u64 max via positive-double max (key high word = finite positive float bits
// -> double exponent never all-ones, sign 0; positive doubles order == bit order).
__device__ __forceinline__ u64 u64fmax(u64 a, u64 b) {
  double ad = __longlong_as_double((long long)a);
  double bd = __longlong_as_double((long long)b);
  return (u64)(long long)__double_as_longlong(fmax(ad, bd));
}

template <int CTRL, int RM>
__device__ __forceinline__ u64 dppmax(u64 cur) {
  int slo = __builtin_amdgcn_update_dpp(0, (int)(u32)cur, CTRL, RM, 0xf, false);
  int shi = __builtin_amdgcn_update_dpp(0, (int)(u32)(cur >> 32), CTRL, RM, 0xf, false);
  u64 o = ((u64)(u32)shi << 32) | (u32)slo;
  return u64fmax(o, cur);
}

// packed 2xf32 ops (VOP3P). IEEE RNE per element, no contraction (opaque asm).
__device__ __forceinline__ f32x2 pk_add(f32x2 a, f32x2 b) {
  f32x2 d;
  asm("v_pk_add_f32 %0, %1, %2" : "=v"(d) : "v"(a), "v"(b));
  return d;
}
__device__ __forceinline__ f32x2 pk_mul(f32x2 a, f32x2 b) {
  f32x2 d;
  asm("v_pk_mul_f32 %0, %1, %2" : "=v"(d) : "v"(a), "v"(b));
  return d;
}

__global__ __launch_bounds__(1024, 4)
void fused_kernel(const float* __restrict__ pos,
                  const float* __restrict__ xs,
                  const float* __restrict__ ys,
                  const float* __restrict__ zs,
                  const int* __restrict__ oidv,
                  int* __restrict__ idx,
                  int* __restrict__ src,
                  int* __restrict__ valid,
                  const float* __restrict__ W1,
                  const float* __restrict__ b1,
                  const float* __restrict__ W2,
                  const float* __restrict__ b2,
                  float* __restrict__ out,
                  int* __restrict__ prog) {
  __shared__ __align__(16) unsigned char smem[SMEM_SZ];
  const int t = threadIdx.x;

  if (blockIdx.x == 0) {
    // =================== FPS (R24 body, frozen; + prog publish) ===================
    float2* s_yz = (float2*)smem;
    u64 (*s_k)[16] = (u64 (*)[16])(smem + OFF_SK);
    const int wv = t >> 6;
    const int base0 = t * PPT;
    const float4* __restrict__ xv = (const float4*)(xs + base0);
    const float4* __restrict__ yv = (const float4*)(ys + base0);
    const float4* __restrict__ zv = (const float4*)(zs + base0);
    const int4*   __restrict__ ov = (const int4*)(oidv + base0);

#define DECLP(J) float md##J;
    PT_LIST(DECLP)
#undef DECLP
#define DECLC(J) u32 C##J;
    PT_LIST(DECLC)
#undef DECLC
#define DECLX(P) f32x2 X##P; f32x2 Y##P; f32x2 Z##P;
    PR_LIST(DECLX)
#undef DECLX

    float bnx = 3.4e38f, bxx = -3.4e38f, bny = 3.4e38f, bxy = -3.4e38f,
          bnz = 3.4e38f, bxz = -3.4e38f;

#define INIT4(G, J0, J1, J2, J3, PA, PB) { \
    float4 vx = xv[G], vy = yv[G], vz = zv[G]; int4 vo = ov[G]; \
    md##J0 = 3.402823466e38f; md##J1 = 3.402823466e38f; \
    md##J2 = 3.402823466e38f; md##J3 = 3.402823466e38f; \
    X##PA.x = vx.x; X##PA.y = vx.y; X##PB.x = vx.z; X##PB.y = vx.w; \
    Y##PA.x = vy.x; Y##PA.y = vy.y; Y##PB.x = vy.z; Y##PB.y = vy.w; \
    Z##PA.x = vz.x; Z##PA.y = vz.y; Z##PB.x = vz.z; Z##PB.y = vz.w; \
    s_yz[J0 * FPS_T + t] = make_float2(vy.x, vz.x); \
    s_yz[J1 * FPS_T + t] = make_float2(vy.y, vz.y); \
    s_yz[J2 * FPS_T + t] = make_float2(vy.z, vz.z); \
    s_yz[J3 * FPS_T + t] = make_float2(vy.w, vz.w); \
    C##J0 = ((16383u - (u32)vo.x) << 14) | (u32)(base0 + J0); \
    C##J1 = ((16383u - (u32)vo.y) << 14) | (u32)(base0 + J1); \
    C##J2 = ((16383u - (u32)vo.z) << 14) | (u32)(base0 + J2); \
    C##J3 = ((16383u - (u32)vo.w) << 14) | (u32)(base0 + J3); \
    bnx = fminf(bnx, fminf(fminf(vx.x, vx.y), fminf(vx.z, vx.w))); \
    bxx = fmaxf(bxx, fmaxf(fmaxf(vx.x, vx.y), fmaxf(vx.z, vx.w))); \
    bny = fminf(bny, fminf(fminf(vy.x, vy.y), fminf(vy.z, vy.w))); \
    bxy = fmaxf(bxy, fmaxf(fmaxf(vy.x, vy.y), fmaxf(vy.z, vy.w))); \
    bnz = fminf(bnz, fminf(fminf(vz.x, vz.y), fminf(vz.z, vz.w))); \
    bxz = fmaxf(bxz, fmaxf(fmaxf(vz.x, vz.y), fmaxf(vz.z, vz.w))); }
    G4_LIST(INIT4)
#undef INIT4

    // key = md_bits<<32 | (16383-oid)<<14 | sidx. Lex max == numpy argmax.
    u64 ckey = 0;
    u64 wklast = 0;
    float cmaxf = 3.402823466e38f;
    float cx = pos[0], cy = pos[1], cz = pos[2];
    if (t == 0) idx[0] = 0;
    __syncthreads();

    for (int k = 0; k < N_S - 1; ++k) {
      float dxl = fmaxf(fmaxf(bnx - cx, cx - bxx), 0.0f);
      float dyl = fmaxf(fmaxf(bny - cy, cy - bxy), 0.0f);
      float dzl = fmaxf(fmaxf(bnz - cz, cz - bxz), 0.0f);
      float lb2 = dxl * dxl + dyl * dyl + dzl * dzl;
      bool act = (0.99f * lb2 < cmaxf);

      if (__ballot(act)) {
        if (act) {
          f32x2 ncx2; ncx2.x = -cx; ncx2.y = -cx;
          f32x2 ncy2; ncy2.x = -cy; ncy2.y = -cy;
          f32x2 ncz2; ncz2.x = -cz; ncz2.y = -cz;
          u64 bkA = 0, bkB = 0;
#define UPDP(P, J0, J1) { \
          f32x2 dx2 = pk_add(X##P, ncx2); \
          f32x2 dy2 = pk_add(Y##P, ncy2); \
          f32x2 dz2 = pk_add(Z##P, ncz2); \
          f32x2 sq = pk_add(pk_mul(dx2, dx2), pk_mul(dy2, dy2)); \
          f32x2 d2 = pk_add(sq, pk_mul(dz2, dz2)); \
          float m0 = fminf(md##J0, d2.x); md##J0 = m0; \
          bkA = u64fmax(bkA, ((u64)__float_as_uint(m0) << 32) | C##J0); \
          float m1 = fminf(md##J1, d2.y); md##J1 = m1; \
          bkB = u64fmax(bkB, ((u64)__float_as_uint(m1) << 32) | C##J1); }
          UPDP(0, 0, 1)  UPDP(1, 2, 3)  UPDP(2, 4, 5)  UPDP(3, 6, 7)
          UPDP(4, 8, 9)  UPDP(5, 10, 11) UPDP(6, 12, 13) UPDP(7, 14, 15)
#undef UPDP
          ckey = u64fmax(bkA, bkB);
          cmaxf = __uint_as_float((u32)(ckey >> 32));
        }
        u64 wk = ckey;
        wk = dppmax<0x111, 0xf>(wk);   // row_shr:1
        wk = dppmax<0x112, 0xf>(wk);   // row_shr:2
        wk = dppmax<0x114, 0xf>(wk);   // row_shr:4
        wk = dppmax<0x118, 0xf>(wk);   // row_shr:8
        wk = dppmax<0x142, 0xa>(wk);   // row_bcast:15 -> rows 1,3
        wk = dppmax<0x143, 0xc>(wk);   // row_bcast:31 -> rows 2,3
        wklast = wk;
      }
      if ((t & 63) == 63) s_k[k & 1][wv] = wklast;
      __syncthreads();

      u64 gk = s_k[k & 1][t & 15];
      gk = dppmax<0x121, 0xf>(gk);   // row_ror:1
      gk = dppmax<0x122, 0xf>(gk);   // row_ror:2
      gk = dppmax<0x124, 0xf>(gk);   // row_ror:4
      gk = dppmax<0x128, 0xf>(gk);   // row_ror:8
      u32 glo = (u32)__builtin_amdgcn_readfirstlane((int)(u32)gk);
      u32 ghi = (u32)__builtin_amdgcn_readfirstlane((int)(u32)(gk >> 32));
      u64 gmax = ((u64)ghi << 32) | glo;
      int sidx = (int)(gmax & 16383u);
      if (t == 0) {
        idx[k + 1] = 16383 - (int)((gmax >> 14) & 16383u);
        // publish at chunk boundaries (k+2 multiple of 32): RELEASE emits
        // buffer_wbl2 (writeback, no invalidate) on this XCD -> idx reaches
        // the L3 coherence point before the counter store; fps's clean L2
        // lines (xs/pos) stay resident.
        if ((k & 31) == 30)
          __hip_atomic_store(prog, k + 2, __ATOMIC_RELEASE, __HIP_MEMORY_SCOPE_AGENT);
      }
      int cell = (sidx & (PPT - 1)) * FPS_T + (sidx >> 4);
      cx = xs[sidx];
      float2 yz = s_yz[cell];
      cy = yz.x;
      cz = yz.y;
    }
  } else {
    // =================== worker: kNN + MLP per ready chunk ===================
    const int wid = blockIdx.x - 1;   // 0..WRK-1
    float4* s_p = (float4*)smem;
    float (*spd)[KPAD] = (float (*)[KPAD])(smem + OFF_SPD);
    int   (*spi)[KPAD] = (int (*)[KPAD])(smem + OFF_SPI);
    float* sW2T = (float*)(smem + OFF_W2T);
    float* sW1  = (float*)(smem + OFF_W1);
    float* sb1  = (float*)(smem + OFF_B1);
    int*   sprog = (int*)(smem + OFF_PROG);
    float* msh1  = (float*)(smem + OFF_SPD);   // [8][NB][CHID], after merge
    float* msrel = (float*)(smem + OFF_SPI);   // [8][NB][3], after merge

    // stage W2 transposed (stride W2S) + W1 + b1; zero a tail-row slice.
    // All overlapped with fps (no dependency yet).
    for (int e = t; e < CHID * COUT; e += 1024) {
      int kk = e >> 7, c = e & (COUT - 1);
      sW2T[c * W2S + kk] = W2[e];
    }
    if (t < 3 * CHID) sW1[t] = W1[t];
    if (t < CHID) sb1[t] = b1[t];
    {
      float4* outv = (float4*)(out + (size_t)N_S * COUT);
      const int cnt = (N_PTS - N_S) * COUT / 4;
      for (int j = wid * 1024 + t; j < cnt; j += WRK * 1024)
        outv[j] = make_float4(0.f, 0.f, 0.f, 0.f);
    }
    __syncthreads();

    for (int gc = wid; gc < NCHK; gc += WRK) {
      // ---- wait for fps to publish this chunk's 32 centers.
      // RELAXED poll: agent-scope atomic load bypasses the (non-coherent) L2
      // and reads the L3 coherence point -> NO buffer_inv, no L2 trashing.
      // Seeing prog>=need implies the release's wbl2 completed -> idx is in L3.
      const int need = gc * 32 + 32;
      for (;;) {
        if (t == 0) *sprog = __hip_atomic_load(prog, __ATOMIC_RELAXED, __HIP_MEMORY_SCOPE_AGENT);
        __syncthreads();
        if (*sprog >= need) break;
        __builtin_amdgcn_s_sleep(32);
        __syncthreads();
      }
      // ---- kNN (R25 body): 32 centers x 32 splits
      const int sp = t >> 5;
      const int cl = t & 31;
      const int i = gc * 32 + cl;
      // agent-scope relaxed atomic: reads the L3 coherence point directly
      const int ci = __hip_atomic_load(idx + i, __ATOMIC_RELAXED, __HIP_MEMORY_SCOPE_AGENT);
      const float cx = pos[3 * ci], cy = pos[3 * ci + 1], cz = pos[3 * ci + 2];
      float nd[NB]; int ni[NB];
#pragma unroll
      for (int q = 0; q < NB; ++q) { nd[q] = 3.402823466e38f; ni[q] = 0x7fffffff; }

      for (int base = 0; base < N_PTS; base += KTILE) {
        __syncthreads();
        for (int j = t; j < KTILE; j += 1024) {
          int pnt = base + j;
          s_p[j] = make_float4(pos[3 * pnt], pos[3 * pnt + 1], pos[3 * pnt + 2], 0.f);
        }
        __syncthreads();
        for (int j = sp; j < KTILE; j += KNS) {
          float4 q4 = s_p[j];
          float dx = __fsub_rn(cx, q4.x);
          float dy = __fsub_rn(cy, q4.y);
          float dz = __fsub_rn(cz, q4.z);
          float d2 = __fadd_rn(__fadd_rn(__fmul_rn(dx, dx), __fmul_rn(dy, dy)), __fmul_rn(dz, dz));
          if (d2 < nd[NB - 1]) {
            float cd = d2; int cp = base + j;
#pragma unroll
            for (int q = 0; q < NB; ++q) {
              bool sw = (cd < nd[q]) || (cd == nd[q] && cp < ni[q]);
              if (sw) { float td = nd[q]; int tp = ni[q]; nd[q] = cd; ni[q] = cp; cd = td; cp = tp; }
            }
          }
        }
      }
#pragma unroll
      for (int q = 0; q < NB; ++q) { spd[cl][sp * NB + q] = nd[q]; spi[cl][sp * NB + q] = ni[q]; }
      __syncthreads();
      if (sp == 0) {
        int cur[KNS];
#pragma unroll
        for (int s = 0; s < KNS; ++s) cur[s] = 0;
        int vb = 0;
        for (int q = 0; q < NB; ++q) {
          float bd = 3.402823466e38f; int bi = 0x7fffffff; int bsl = 0;
#pragma unroll
          for (int s = 0; s < KNS; ++s) {
            float d = spd[cl][s * NB + cur[s]]; int id = spi[cl][s * NB + cur[s]];
            if (d < bd || (d == bd && id < bi)) { bd = d; bi = id; bsl = s; }
          }
#pragma unroll
          for (int s = 0; s < KNS; ++s) cur[s] += (s == bsl) ? 1 : 0;
          src[i * NB + q] = bi;
          if (bd <= R2) vb |= (1 << q);
        }
        valid[i] = vb;
      }
      __syncthreads();

      // ---- MLP (R26 math, kk-ascending fmaf): 4 rounds x 8 centers x 128 ch
      for (int r = 0; r < 4; ++r) {
        const int c8 = t >> 7;          // 0..7
        const int ch = t & 127;
        const int im = gc * 32 + r * 8 + c8;
        if (ch < NB) {
          int s = src[im * NB + ch];
          // reference subtracts pos[:s] row im, NOT the sampled center
          msrel[(c8 * NB + ch) * 3 + 0] = pos[3 * s + 0] - pos[3 * im + 0];
          msrel[(c8 * NB + ch) * 3 + 1] = pos[3 * s + 1] - pos[3 * im + 1];
          msrel[(c8 * NB + ch) * 3 + 2] = pos[3 * s + 2] - pos[3 * im + 2];
        }
        __syncthreads();
        for (int e = t; e < 8 * NB * CHID; e += 1024) {
          int kk = e & 63;
          int n = (e >> 6) % NB;
          int cc = e / (NB * CHID);
          float a = sb1[kk] + msrel[(cc * NB + n) * 3 + 0] * sW1[kk]
                            + msrel[(cc * NB + n) * 3 + 1] * sW1[64 + kk]
                            + msrel[(cc * NB + n) * 3 + 2] * sW1[128 + kk];
          msh1[(cc * NB + n) * CHID + kk] = fmaxf(a, 0.0f);
        }
        __syncthreads();
        {
          const int vmask = valid[im];
          const float bb = b2[ch];
          float m = 0.0f;
          bool any = false;
          for (int n = 0; n < NB; ++n) {
            if (vmask & (1 << n)) {
              float acc = bb;
#pragma unroll
              for (int g = 0; g < 16; ++g) {
                float4 h = *(const float4*)&msh1[(c8 * NB + n) * CHID + 4 * g];
                float4 w = *(const float4*)&sW2T[ch * W2S + 4 * g];
                acc = fmaf(h.x, w.x, acc);
                acc = fmaf(h.y, w.y, acc);
                acc = fmaf(h.z, w.z, acc);
                acc = fmaf(h.w, w.w, acc);
              }
              m = any ? fmaxf(m, acc) : acc;
              any = true;
            }
          }
          out[(size_t)im * COUT + ch] = any ? m : 0.0f;
        }
        __syncthreads();
      }
    }
  }
}

// ======================= launch =======================
extern "C" void kernel_launch(void* const* d_in, const int* in_sizes, int n_in,
                              void* d_out, int out_size, void* d_ws, size_t ws_size,
                              hipStream_t stream) {
  (void)in_sizes; (void)n_in; (void)out_size; (void)ws_size;
  const float* pos = (const float*)d_in[0];
  const float* W1 = (const float*)d_in[2];
  const float* b1 = (const float*)d_in[3];
  const float* W2 = (const float*)d_in[4];
  const float* b2 = (const float*)d_in[5];
  float* out = (float*)d_out;

  char* ws = (char*)d_ws;
  int*   idx   = (int*)ws;                 ws += (size_t)N_S * 4;          // 32 KB
  int*   src   = (int*)ws;                 ws += (size_t)N_S * NB * 4;     // 320 KB
  int*   valid = (int*)ws;                 ws += (size_t)N_S * 4;          // 32 KB
  float* xs    = (float*)ws;               ws += (size_t)N_PTS * 4;        // 64 KB
  float* ys    = (float*)ws;               ws += (size_t)N_PTS * 4;
  float* zs    = (float*)ws;               ws += (size_t)N_PTS * 4;
  int*   oid   = (int*)ws;                 ws += (size_t)N_PTS * 4;
  int*   progp = (int*)ws;                 ws += 16;                       // progress counter
  // sort temporaries alias the src region (sort completes before knn writes src)
  int* cellid = src;                 // N_PTS ints = 64 KB  (src region is 320 KB)
  int* hist   = src + N_PTS;         // NCELL ints = 16 KB
  int* basebuf= src + N_PTS + NCELL; // NCELL ints = 16 KB

  hipMemsetAsync(hist, 0, (size_t)NCELL * 4, stream);
  hipMemsetAsync(progp, 0, 4, stream);
  cell_kernel<<<N_PTS / 256, 256, 0, stream>>>(pos, cellid, hist);
  scan_kernel<<<1, 1024, 0, stream>>>(hist, basebuf);
  scatter_kernel<<<N_PTS / 256, 256, 0, stream>>>(pos, cellid, basebuf, xs, ys, zs, oid);
  fused_kernel<<<1 + WRK, 1024, 0, stream>>>(pos, xs, ys, zs, oid, idx, src, valid,
                                             W1, b1, W2, b2, out, progp);
}